// Round 1
// baseline (694.351 us; speedup 1.0000x reference)
//
#include <hip/hip_runtime.h>

// GRU encoder: B=64, T=512, F=64, H=256, D=64.
// Plan:
//   k1: xproj[b,t,g] = x[b,t,:] @ kernel[:,g] + bias[g]  -> f16 in d_ws (48 MiB)
//   k2: per-batch sequential scan, 64 blocks x 1024 threads.
//       W_rec (256x768) cached per-thread in registers as f16 pairs (96 VGPRs),
//       matvec via v_dot2_f32_f16, h in LDS (f32 + f16 mirror), 2 barriers/step.
//       Dense head (h_last @ dense_w + dense_b -> tanh) fused at the end.

typedef _Float16 half2_t __attribute__((ext_vector_type(2)));
typedef _Float16 f16x8_t __attribute__((ext_vector_type(8)));

#define LOG2E 1.4426950408889634f

__device__ __forceinline__ float fast_sigmoid(float x) {
  float e = __builtin_amdgcn_exp2f(-x * LOG2E);
  return __builtin_amdgcn_rcpf(1.0f + e);
}
__device__ __forceinline__ float fast_tanh(float x) {
  // tanh(x) = 1 - 2/(exp(2x)+1); saturates correctly at +/-inf
  float e = __builtin_amdgcn_exp2f(x * (2.0f * LOG2E));
  return 1.0f - 2.0f * __builtin_amdgcn_rcpf(1.0f + e);
}

// ---------------------------------------------------------------------------
// Kernel 1: xproj GEMM.  C(32768x768) = A(32768x64) @ B(64x768) + bias, f16 out.
// Tile 128x128, block 256 threads, 8x8 microtile, K=64 single pass.
// ---------------------------------------------------------------------------
__global__ __launch_bounds__(256) void xproj_gemm(
    const float* __restrict__ x, const float* __restrict__ kmat,
    const float* __restrict__ bias, _Float16* __restrict__ xp) {
  __shared__ float Asm[64][132];  // [k][row], stride 132 keeps 16B alignment
  __shared__ float Bsm[64][132];  // [k][col]
  const int tid = threadIdx.x;
  const int rb = blockIdx.x * 128;
  const int cb = blockIdx.y * 128;

  // Load A tile transposed: rows rb..rb+127, k 0..63
  {
    int k4 = (tid & 15) * 4;
    int r0 = tid >> 4;
#pragma unroll
    for (int it = 0; it < 8; ++it) {
      int r = r0 + it * 16;
      float4 v = *(const float4*)(x + (size_t)(rb + r) * 64 + k4);
      Asm[k4 + 0][r] = v.x;
      Asm[k4 + 1][r] = v.y;
      Asm[k4 + 2][r] = v.z;
      Asm[k4 + 3][r] = v.w;
    }
  }
  // Load B tile: k 0..63, cols cb..cb+127
  {
    int c4 = (tid & 31) * 4;
    int k0 = tid >> 5;
#pragma unroll
    for (int it = 0; it < 8; ++it) {
      int k = k0 + it * 8;
      float4 v = *(const float4*)(kmat + (size_t)k * 768 + cb + c4);
      *(float4*)(&Bsm[k][c4]) = v;
    }
  }
  __syncthreads();

  const int tx = tid & 15, ty = tid >> 4;
  const int c0 = tx * 8, r0 = ty * 8;
  float acc[8][8];
  {
    float bz[8];
#pragma unroll
    for (int j = 0; j < 8; ++j) bz[j] = bias[cb + c0 + j];
#pragma unroll
    for (int i = 0; i < 8; ++i)
#pragma unroll
      for (int j = 0; j < 8; ++j) acc[i][j] = bz[j];
  }

#pragma unroll 8
  for (int k = 0; k < 64; ++k) {
    float a[8], bv[8];
    *(float4*)(&a[0]) = *(const float4*)(&Asm[k][r0]);
    *(float4*)(&a[4]) = *(const float4*)(&Asm[k][r0 + 4]);
    *(float4*)(&bv[0]) = *(const float4*)(&Bsm[k][c0]);
    *(float4*)(&bv[4]) = *(const float4*)(&Bsm[k][c0 + 4]);
#pragma unroll
    for (int i = 0; i < 8; ++i)
#pragma unroll
      for (int j = 0; j < 8; ++j) acc[i][j] = fmaf(a[i], bv[j], acc[i][j]);
  }

#pragma unroll
  for (int i = 0; i < 8; ++i) {
    f16x8_t o;
#pragma unroll
    for (int j = 0; j < 8; ++j) o[j] = (_Float16)acc[i][j];
    *(f16x8_t*)(xp + (size_t)(rb + r0 + i) * 768 + cb + c0) = o;
  }
}

// ---------------------------------------------------------------------------
// Kernel 2: GRU scan. One block per batch row. 1024 threads = 16 waves.
// Thread (c = tid>>8 in 0..3, col = tid&255) holds W_rec[k in 64c..64c+63]
// for columns {col, col+256, col+512} as 96 packed f16 pairs (registers).
// ---------------------------------------------------------------------------
__global__ __launch_bounds__(1024, 4) void gru_scan(
    const _Float16* __restrict__ xp, const float* __restrict__ wr,
    const float* __restrict__ dw, const float* __restrict__ db,
    float* __restrict__ out, float* __restrict__ state) {
  __shared__ float part[4 * 768];
  __shared__ float hbuf[256];
  __shared__ alignas(16) _Float16 hhalf[256];
  __shared__ _Float16 xrow[768];

  const int tid = threadIdx.x;
  const int b = blockIdx.x;
  const int c = tid >> 8;     // k-chunk 0..3
  const int col = tid & 255;  // output column within gate

  // --- load W_rec fragment into registers as f16 pairs (coalesced 256B/wave)
  half2_t w2[3][32];
#pragma unroll
  for (int q = 0; q < 3; ++q) {
    const float* wp = wr + (size_t)(c * 64) * 768 + col + q * 256;
#pragma unroll
    for (int j = 0; j < 32; ++j) {
      float wa = wp[(size_t)(2 * j) * 768];
      float wb = wp[(size_t)(2 * j + 1) * 768];
      half2_t p;
      p[0] = (_Float16)wa;
      p[1] = (_Float16)wb;
      w2[q][j] = p;
    }
  }

  if (tid < 256) {
    hbuf[tid] = 0.0f;
    hhalf[tid] = (_Float16)0.0f;
  }
  __syncthreads();

  const _Float16* xpb = xp + (size_t)b * 512 * 768;
  float* outb = out + (size_t)b * 512 * 256;

  for (int t = 0; t < 512; ++t) {
    // issue x-row load early (consumed by gate phase after the barrier)
    _Float16 xv = (_Float16)0.0f;
    if (tid < 768) xv = xpb[(size_t)t * 768 + tid];

    // --- matvec: rec[col+256q] partial over k-chunk c
    float a0 = 0.0f, a1 = 0.0f, a2 = 0.0f;
    const int4* hp = (const int4*)(hhalf) + c * 8;  // 16B broadcast reads
#pragma unroll
    for (int g = 0; g < 8; ++g) {
      int4 hv = hp[g];
      half2_t p0 = __builtin_bit_cast(half2_t, hv.x);
      half2_t p1 = __builtin_bit_cast(half2_t, hv.y);
      half2_t p2 = __builtin_bit_cast(half2_t, hv.z);
      half2_t p3 = __builtin_bit_cast(half2_t, hv.w);
      a0 = __builtin_amdgcn_fdot2(p0, w2[0][g * 4 + 0], a0, false);
      a0 = __builtin_amdgcn_fdot2(p1, w2[0][g * 4 + 1], a0, false);
      a0 = __builtin_amdgcn_fdot2(p2, w2[0][g * 4 + 2], a0, false);
      a0 = __builtin_amdgcn_fdot2(p3, w2[0][g * 4 + 3], a0, false);
      a1 = __builtin_amdgcn_fdot2(p0, w2[1][g * 4 + 0], a1, false);
      a1 = __builtin_amdgcn_fdot2(p1, w2[1][g * 4 + 1], a1, false);
      a1 = __builtin_amdgcn_fdot2(p2, w2[1][g * 4 + 2], a1, false);
      a1 = __builtin_amdgcn_fdot2(p3, w2[1][g * 4 + 3], a1, false);
      a2 = __builtin_amdgcn_fdot2(p0, w2[2][g * 4 + 0], a2, false);
      a2 = __builtin_amdgcn_fdot2(p1, w2[2][g * 4 + 1], a2, false);
      a2 = __builtin_amdgcn_fdot2(p2, w2[2][g * 4 + 2], a2, false);
      a2 = __builtin_amdgcn_fdot2(p3, w2[2][g * 4 + 3], a2, false);
    }
    part[c * 768 + col] = a0;
    part[c * 768 + col + 256] = a1;
    part[c * 768 + col + 512] = a2;
    if (tid < 768) xrow[tid] = xv;
    __syncthreads();

    // --- gates: waves 0..3 (one per SIMD)
    if (tid < 256) {
      const int i = tid;
      float rz = part[i] + part[768 + i] + part[1536 + i] + part[2304 + i];
      float rr = part[256 + i] + part[768 + 256 + i] + part[1536 + 256 + i] +
                 part[2304 + 256 + i];
      float rh = part[512 + i] + part[768 + 512 + i] + part[1536 + 512 + i] +
                 part[2304 + 512 + i];
      float xz = (float)xrow[i];
      float xr = (float)xrow[256 + i];
      float xh = (float)xrow[512 + i];
      float z = fast_sigmoid(xz + rz);
      float r = fast_sigmoid(xr + rr);
      float hh = fast_tanh(xh + r * rh);
      float hold = hbuf[i];
      float hnew = z * hold + (1.0f - z) * hh;
      hbuf[i] = hnew;
      hhalf[i] = (_Float16)hnew;
      outb[(size_t)t * 256 + i] = hnew;
    }
    __syncthreads();
  }

  // --- dense head: state[b,:] = tanh(h_last @ dense_w + dense_b)
  if (tid < 64) {
    float acc = db[tid];
#pragma unroll 8
    for (int k = 0; k < 256; ++k) acc = fmaf(hbuf[k], dw[k * 64 + tid], acc);
    state[(size_t)b * 64 + tid] = fast_tanh(acc);
  }
}

// ---------------------------------------------------------------------------
extern "C" void kernel_launch(void* const* d_in, const int* in_sizes, int n_in,
                              void* d_out, int out_size, void* d_ws,
                              size_t ws_size, hipStream_t stream) {
  const float* x = (const float*)d_in[0];     // (64,512,64)
  const float* kmat = (const float*)d_in[1];  // (64,768)
  const float* wr = (const float*)d_in[2];    // (256,768)
  const float* bias = (const float*)d_in[3];  // (768,)
  const float* dw = (const float*)d_in[4];    // (256,64)
  const float* db = (const float*)d_in[5];    // (64,)

  float* out = (float*)d_out;                       // (64,512,256)
  float* state = out + (size_t)64 * 512 * 256;      // (64,64)
  _Float16* xp = (_Float16*)d_ws;                   // 64*512*768 f16 = 48 MiB

  dim3 gg(32768 / 128, 768 / 128);
  xproj_gemm<<<gg, 256, 0, stream>>>(x, kmat, bias, xp);
  gru_scan<<<64, 1024, 0, stream>>>(xp, wr, dw, db, out, state);
}

// Round 2
// 661.879 us; speedup vs baseline: 1.0491x; 1.0491x over previous
//
#include <hip/hip_runtime.h>

// GRU encoder: B=64, T=512, F=64, H=256, D=64.
//   k1: xproj = x @ kernel + bias -> f16 in d_ws, dot2-based GEMM, 4 blk/CU.
//   k2: per-batch scan, 64 blocks x 1024 threads. W_rec in VGPRs as f16
//       pairs (96 regs/thread); h prefetched 1 int4 ahead (live set <=128
//       VGPRs so the compiler does NOT demote weights to AGPRs).

typedef _Float16 half2_t __attribute__((ext_vector_type(2)));
typedef _Float16 f16x4_t __attribute__((ext_vector_type(4)));

#define LOG2E 1.4426950408889634f

__device__ __forceinline__ float fast_sigmoid(float x) {
  float e = __builtin_amdgcn_exp2f(-x * LOG2E);
  return __builtin_amdgcn_rcpf(1.0f + e);
}
__device__ __forceinline__ float fast_tanh(float x) {
  float e = __builtin_amdgcn_exp2f(x * (2.0f * LOG2E));
  return 1.0f - 2.0f * __builtin_amdgcn_rcpf(1.0f + e);
}

// ---------------------------------------------------------------------------
// Kernel 1: xproj GEMM.  C(32768x768) = A(32768x64) @ B(64x768) + bias.
// f16-pair LDS staging (33.8 KB -> 4 blocks/CU), v_dot2_f32_f16 inner loop.
// Microtile 8 rows x (4+4 split cols): B reads are b64, conflict-free.
// ---------------------------------------------------------------------------
__global__ __launch_bounds__(256, 4) void xproj_gemm(
    const float* __restrict__ x, const float* __restrict__ kmat,
    const float* __restrict__ bias, _Float16* __restrict__ xp) {
  __shared__ half2_t As2[32][132];  // [kpair][row]
  __shared__ half2_t Bs2[32][132];  // [kpair][col]
  const int tid = threadIdx.x;
  const int rb = blockIdx.x * 128;
  const int cb = blockIdx.y * 128;

  // Stage A (x rows rb..rb+127, k 0..63) as k-pairs of f16.
  {
    const int k4 = (tid & 15) * 4;
    const int r0 = tid >> 4;
#pragma unroll
    for (int p = 0; p < 8; ++p) {
      int r = r0 + p * 16;
      float4 v = *(const float4*)(x + (size_t)(rb + r) * 64 + k4);
      half2_t lo, hi;
      lo[0] = (_Float16)v.x; lo[1] = (_Float16)v.y;
      hi[0] = (_Float16)v.z; hi[1] = (_Float16)v.w;
      As2[k4 / 2][r] = lo;
      As2[k4 / 2 + 1][r] = hi;
    }
  }
  // Stage B (kernel rows 0..63, cols cb..cb+127) as k-pairs of f16.
  {
    const int c4 = (tid & 31) * 4;
    const int kp0 = tid >> 5;
#pragma unroll
    for (int p = 0; p < 4; ++p) {
      int kp = kp0 + p * 8;
      float4 va = *(const float4*)(kmat + (size_t)(2 * kp) * 768 + cb + c4);
      float4 vb = *(const float4*)(kmat + (size_t)(2 * kp + 1) * 768 + cb + c4);
      half2_t o0, o1, o2, o3;
      o0[0] = (_Float16)va.x; o0[1] = (_Float16)vb.x;
      o1[0] = (_Float16)va.y; o1[1] = (_Float16)vb.y;
      o2[0] = (_Float16)va.z; o2[1] = (_Float16)vb.z;
      o3[0] = (_Float16)va.w; o3[1] = (_Float16)vb.w;
      Bs2[kp][c4 + 0] = o0;
      Bs2[kp][c4 + 1] = o1;
      Bs2[kp][c4 + 2] = o2;
      Bs2[kp][c4 + 3] = o3;
    }
  }
  __syncthreads();

  const int tx = tid & 15, ty = tid >> 4;
  const int r0 = ty * 8;
  const int c0 = tx * 4;  // cols {c0..c0+3} and {64+c0..64+c0+3}
  float acc[8][8];
  {
    float4 b0 = *(const float4*)(bias + cb + c0);
    float4 b1 = *(const float4*)(bias + cb + 64 + c0);
    float bz[8] = {b0.x, b0.y, b0.z, b0.w, b1.x, b1.y, b1.z, b1.w};
#pragma unroll
    for (int i = 0; i < 8; ++i)
#pragma unroll
      for (int j = 0; j < 8; ++j) acc[i][j] = bz[j];
  }

#pragma unroll 2
  for (int kp = 0; kp < 32; ++kp) {
    half2_t a2[8], b2[8];
    *(int4*)(&a2[0]) = *(const int4*)(&As2[kp][r0]);
    *(int4*)(&a2[4]) = *(const int4*)(&As2[kp][r0 + 4]);
    *(int2*)(&b2[0]) = *(const int2*)(&Bs2[kp][c0]);
    *(int2*)(&b2[2]) = *(const int2*)(&Bs2[kp][c0 + 2]);
    *(int2*)(&b2[4]) = *(const int2*)(&Bs2[kp][64 + c0]);
    *(int2*)(&b2[6]) = *(const int2*)(&Bs2[kp][64 + c0 + 2]);
#pragma unroll
    for (int i = 0; i < 8; ++i)
#pragma unroll
      for (int j = 0; j < 8; ++j)
        acc[i][j] = __builtin_amdgcn_fdot2(a2[i], b2[j], acc[i][j], false);
  }

#pragma unroll
  for (int i = 0; i < 8; ++i) {
    f16x4_t o0, o1;
#pragma unroll
    for (int j = 0; j < 4; ++j) {
      o0[j] = (_Float16)acc[i][j];
      o1[j] = (_Float16)acc[i][4 + j];
    }
    _Float16* dst = xp + (size_t)(rb + r0 + i) * 768 + cb;
    *(f16x4_t*)(dst + c0) = o0;
    *(f16x4_t*)(dst + 64 + c0) = o1;
  }
}

// ---------------------------------------------------------------------------
// Kernel 2: GRU scan. One block per batch row. 1024 threads = 16 waves.
// Thread (c = tid>>8, col = tid&255) holds W_rec[k in 64c..64c+63] for
// columns {col, col+256, col+512} as 96 packed f16 pairs in VGPRs.
// h live-range limited to 2 int4 via prefetch + sched_barrier(1).
// ---------------------------------------------------------------------------
__global__ __launch_bounds__(1024, 4) void gru_scan(
    const _Float16* __restrict__ xp, const float* __restrict__ wr,
    const float* __restrict__ dw, const float* __restrict__ db,
    float* __restrict__ out, float* __restrict__ state) {
  __shared__ float part[4 * 768];
  __shared__ float hbuf[256];
  __shared__ alignas(16) _Float16 hhalf[256];
  __shared__ _Float16 xrow[768];

  const int tid = threadIdx.x;
  const int b = blockIdx.x;
  const int c = tid >> 8;     // k-chunk 0..3
  const int col = tid & 255;  // output column within gate

  // --- load W_rec fragment into registers as f16 pairs (96 VGPRs)
  half2_t w2[3][32];
#pragma unroll
  for (int q = 0; q < 3; ++q) {
    const float* wp = wr + (size_t)(c * 64) * 768 + col + q * 256;
#pragma unroll
    for (int j = 0; j < 32; ++j) {
      float wa = wp[(size_t)(2 * j) * 768];
      float wb = wp[(size_t)(2 * j + 1) * 768];
      half2_t p;
      p[0] = (_Float16)wa;
      p[1] = (_Float16)wb;
      w2[q][j] = p;
    }
  }

  if (tid < 256) hhalf[tid] = (_Float16)0.0f;
  __syncthreads();

  const _Float16* xpb = xp + (size_t)b * 512 * 768;
  float* outb = out + (size_t)b * 512 * 256;
  const int4* hp2 = (const int4*)hhalf + c * 8;
  float hprev = 0.0f;

  for (int t = 0; t < 512; ++t) {
    // x-row load issued early; consumed by gate phase after barrier 1
    _Float16 xv = (_Float16)0.0f;
    if (tid < 768) xv = xpb[(size_t)t * 768 + tid];

    float a0 = 0.0f, a1 = 0.0f, a2 = 0.0f;
    int4 hv = hp2[0];
#pragma unroll
    for (int g = 0; g < 8; ++g) {
      __builtin_amdgcn_sched_barrier(1);  // pin ds_reads: prefetch depth 1
      int4 hn = hv;
      if (g < 7) hn = hp2[g + 1];
      half2_t p0 = __builtin_bit_cast(half2_t, hv.x);
      half2_t p1 = __builtin_bit_cast(half2_t, hv.y);
      half2_t p2 = __builtin_bit_cast(half2_t, hv.z);
      half2_t p3 = __builtin_bit_cast(half2_t, hv.w);
      a0 = __builtin_amdgcn_fdot2(p0, w2[0][g * 4 + 0], a0, false);
      a0 = __builtin_amdgcn_fdot2(p1, w2[0][g * 4 + 1], a0, false);
      a0 = __builtin_amdgcn_fdot2(p2, w2[0][g * 4 + 2], a0, false);
      a0 = __builtin_amdgcn_fdot2(p3, w2[0][g * 4 + 3], a0, false);
      a1 = __builtin_amdgcn_fdot2(p0, w2[1][g * 4 + 0], a1, false);
      a1 = __builtin_amdgcn_fdot2(p1, w2[1][g * 4 + 1], a1, false);
      a1 = __builtin_amdgcn_fdot2(p2, w2[1][g * 4 + 2], a1, false);
      a1 = __builtin_amdgcn_fdot2(p3, w2[1][g * 4 + 3], a1, false);
      a2 = __builtin_amdgcn_fdot2(p0, w2[2][g * 4 + 0], a2, false);
      a2 = __builtin_amdgcn_fdot2(p1, w2[2][g * 4 + 1], a2, false);
      a2 = __builtin_amdgcn_fdot2(p2, w2[2][g * 4 + 2], a2, false);
      a2 = __builtin_amdgcn_fdot2(p3, w2[2][g * 4 + 3], a2, false);
      hv = hn;
    }
    part[c * 768 + col] = a0;
    part[c * 768 + col + 256] = a1;
    part[c * 768 + col + 512] = a2;
    if (tid < 768) xrow[tid] = xv;
    __syncthreads();

    // --- gates: waves 0..3. Store of h(t-1) deferred here so its vmcnt
    // drain overlaps gate compute instead of stalling at the barrier.
    if (tid < 256) {
      const int i = tid;
      if (t) outb[(size_t)(t - 1) * 256 + i] = hprev;
      float rz = part[i] + part[768 + i] + part[1536 + i] + part[2304 + i];
      float rr = part[256 + i] + part[768 + 256 + i] + part[1536 + 256 + i] +
                 part[2304 + 256 + i];
      float rh = part[512 + i] + part[768 + 512 + i] + part[1536 + 512 + i] +
                 part[2304 + 512 + i];
      float xz = (float)xrow[i];
      float xr = (float)xrow[256 + i];
      float xh = (float)xrow[512 + i];
      float z = fast_sigmoid(xz + rz);
      float r = fast_sigmoid(xr + rr);
      float hh = fast_tanh(xh + r * rh);
      float hnew = z * hprev + (1.0f - z) * hh;
      hprev = hnew;
      hhalf[i] = (_Float16)hnew;
    }
    __syncthreads();
  }

  if (tid < 256) {
    outb[(size_t)511 * 256 + tid] = hprev;
    hbuf[tid] = hprev;
  }
  __syncthreads();

  // --- dense head: state[b,:] = tanh(h_last @ dense_w + dense_b)
  if (tid < 64) {
    float acc = db[tid];
#pragma unroll 8
    for (int k = 0; k < 256; ++k) acc = fmaf(hbuf[k], dw[k * 64 + tid], acc);
    state[(size_t)b * 64 + tid] = fast_tanh(acc);
  }
}

// ---------------------------------------------------------------------------
extern "C" void kernel_launch(void* const* d_in, const int* in_sizes, int n_in,
                              void* d_out, int out_size, void* d_ws,
                              size_t ws_size, hipStream_t stream) {
  const float* x = (const float*)d_in[0];     // (64,512,64)
  const float* kmat = (const float*)d_in[1];  // (64,768)
  const float* wr = (const float*)d_in[2];    // (256,768)
  const float* bias = (const float*)d_in[3];  // (768,)
  const float* dw = (const float*)d_in[4];    // (256,64)
  const float* db = (const float*)d_in[5];    // (64,)

  float* out = (float*)d_out;                   // (64,512,256)
  float* state = out + (size_t)64 * 512 * 256;  // (64,64)
  _Float16* xp = (_Float16*)d_ws;               // 64*512*768 f16 = 48 MiB

  dim3 gg(32768 / 128, 768 / 128);
  xproj_gemm<<<gg, 256, 0, stream>>>(x, kmat, bias, xp);
  gru_scan<<<64, 1024, 0, stream>>>(xp, wr, dw, db, out, state);
}